// Round 18
// baseline (46.253 us; speedup 1.0000x reference)
//
#include <hip/hip_runtime.h>

typedef __bf16 bf16x8 __attribute__((ext_vector_type(8)));
typedef float f32x4 __attribute__((ext_vector_type(4)));
typedef unsigned short u16;

#define MFMA __builtin_amdgcn_mfma_f32_16x16x32_bf16

__device__ __forceinline__ u16 f2bf_bits(float f) {
  unsigned u = __builtin_bit_cast(unsigned, f);
  u = (u + 0x7fffu + ((u >> 16) & 1u)) >> 16;
  return (u16)u;
}
__device__ __forceinline__ __bf16 f2bf(float f) {
  u16 b = f2bf_bits(f);
  return __builtin_bit_cast(__bf16, b);
}
__device__ __forceinline__ float bf2f(u16 b) {
  return __builtin_bit_cast(float, (unsigned)b << 16);
}

// Barrier that drains ONLY LDS ops (lgkmcnt), leaving global loads (vmcnt) in
// flight across the barrier (T4). Safe when in-flight loads are lane-private.
__device__ __forceinline__ void barrier_lds_only() {
  asm volatile("s_waitcnt lgkmcnt(0)" ::: "memory");
  __builtin_amdgcn_s_barrier();
}

// LDS tiles: logical [R][64] bf16 rows (128 B). XOR-swizzle 16B chunks with row
// to kill the 128B-stride bank conflict on ds_read_b128 (guide G4).
__device__ __forceinline__ int swz_off(int row, int col) {
  return row * 64 + ((((col >> 3) ^ row) & 7) << 3) + (col & 7);
}
__device__ __forceinline__ bf16x8 lds_read8(const __bf16* buf, int row, int col) {
  return *(const bf16x8*)(buf + (row * 64 + ((((col >> 3) ^ row) & 7) << 3)));
}
__device__ __forceinline__ void lds_write8(__bf16* buf, int row, int col, bf16x8 v) {
  *(bf16x8*)(buf + (row * 64 + ((((col >> 3) ^ row) & 7) << 3))) = v;
}

// ---------------- prep: Wt[192][1024] bf16 via coalesced LDS transpose.
__global__ __launch_bounds__(256) void prep_w_kernel(
    const float* __restrict__ Wq, const float* __restrict__ Wk,
    const float* __restrict__ Wv, u16* __restrict__ wtg) {
  __shared__ float tile[64][65];
  const int tid = threadIdx.x;
  const int kt = blockIdx.x & 15;  // 64 k-rows
  const int ct = blockIdx.x >> 4;  // 0=q, 1=k, 2=v
  const float* W = (ct == 0) ? Wq : ((ct == 1) ? Wk : Wv);
  const int k0 = kt * 64;
#pragma unroll
  for (int i = 0; i < 16; ++i) {
    int row = i * 4 + (tid >> 6), col = tid & 63;
    tile[row][col] = W[(size_t)(k0 + row) * 64 + col];
  }
  __syncthreads();
#pragma unroll
  for (int i = 0; i < 16; ++i) {
    int col = i * 4 + (tid >> 6), krow = tid & 63;
    wtg[(size_t)(ct * 64 + col) * 1024 + k0 + krow] = f2bf_bits(tile[krow][col]);
  }
}

// RoPE a (lo,hi) column pair via native v_sin/v_cos (revolutions + v_fract).
__device__ __forceinline__ void rope2(f32x4& lo, f32x4& hi, int i, float t_base) {
  float f = __expf(-(float)i * 0.28782313662425572f);  // 10000^(-i/32)
  const float inv2pi = 0.15915494309189535f;
#pragma unroll
  for (int r = 0; r < 4; ++r) {
    float rev = (t_base + (float)r) * f * inv2pi;
    rev = __builtin_amdgcn_fractf(rev);
    float sn = __builtin_amdgcn_sinf(rev);
    float cs = __builtin_amdgcn_cosf(rev);
    float L = lo[r], H = hi[r];
    lo[r] = L * cs - H * sn;
    hi[r] = H * cs + L * sn;
  }
}

// ---------------- fused QKV projection + RoPE (256 blocks x 64 rows).
// R12-proven shape + XCD-consistent batch mapping: b = bid & 7 puts batch b's
// q/k/vt WRITES on XCD b's L2 — exactly where attn_part (b = idx & 7, R17's
// -4.5us win) reads them. DEPTH-3 x prefetch, LDS-only barriers, W depth-1.
// Tile sets keep RoPE pairs (c,c+32) lane-local.
__global__ __launch_bounds__(512) void qkv_rope_kernel(
    const float* __restrict__ x, const u16* __restrict__ wtg,
    u16* __restrict__ qg, u16* __restrict__ kg, u16* __restrict__ vtg) {
  __shared__ __bf16 xbuf[2][64 * 64];
  __shared__ __bf16 wbuf[2][192 * 64];
  const int tid = threadIdx.x;
  const int w = tid >> 6, l = tid & 63;
  const int wrg = w & 1;
  const int wcg = w >> 1;
  const int lr = l & 15, lg = l >> 4;
  const int b = blockIdx.x & 7;              // XCD-consistent batch mapping
  const int t0 = (blockIdx.x >> 3) * 64;
  const int r0 = b * 2048 + t0;
  constexpr int TM4[4][3] = {{0, 2, 8}, {1, 3, 9}, {4, 6, 10}, {5, 7, 11}};

  f32x4 acc[2][3];
#pragma unroll
  for (int rg = 0; rg < 2; ++rg)
#pragma unroll
    for (int j = 0; j < 3; ++j) acc[rg][j] = (f32x4){0.f, 0.f, 0.f, 0.f};

  const int srow = tid >> 3, sc8 = tid & 7;
  const float* xbase = x + (size_t)(r0 + srow) * 1024 + sc8 * 8;

  float4 xA0, xA1, xB0, xB1, xC0, xC1;
  bf16x8 swr[3];

  auto loadW = [&](int k0) {
#pragma unroll
    for (int s = 0; s < 3; ++s) {
      int id = tid + s * 512;
      swr[s] = *(const bf16x8*)(wtg + (size_t)(id >> 3) * 1024 + k0 + (id & 7) * 8);
    }
  };
  auto writeW = [&](int bsel) {
#pragma unroll
    for (int s = 0; s < 3; ++s) {
      int id = tid + s * 512;
      lds_write8(wbuf[bsel], id >> 3, (id & 7) * 8, swr[s]);
    }
  };
  auto loadX = [&](int step, int sel) {
    const float* p = xbase + (size_t)step * 64;
    if (sel == 0)      { xA0 = *(const float4*)p; xA1 = *(const float4*)(p + 4); }
    else if (sel == 1) { xB0 = *(const float4*)p; xB1 = *(const float4*)(p + 4); }
    else               { xC0 = *(const float4*)p; xC1 = *(const float4*)(p + 4); }
  };
  auto writeX = [&](int bsel, int sel) {
    float4 a0, a1;
    if (sel == 0)      { a0 = xA0; a1 = xA1; }
    else if (sel == 1) { a0 = xB0; a1 = xB1; }
    else               { a0 = xC0; a1 = xC1; }
    bf16x8 v;
    v[0] = f2bf(a0.x); v[1] = f2bf(a0.y); v[2] = f2bf(a0.z); v[3] = f2bf(a0.w);
    v[4] = f2bf(a1.x); v[5] = f2bf(a1.y); v[6] = f2bf(a1.z); v[7] = f2bf(a1.w);
    lds_write8(xbuf[bsel], srow, sc8 * 8, v);
  };

  loadX(0, 0);
  loadW(0);
  writeX(0, 0);
  writeW(0);
  loadX(1, 1);
  loadX(2, 2);
  barrier_lds_only();

#pragma unroll
  for (int s = 0; s < 16; ++s) {
    const int cur = s & 1;
    if (s < 13) loadX(s + 3, s % 3);
    if (s < 15) loadW((s + 1) * 64);
#pragma unroll
    for (int kk = 0; kk < 2; ++kk) {
      bf16x8 a0 = lds_read8(xbuf[cur], wrg * 32 + lr, kk * 32 + lg * 8);
      bf16x8 a1 = lds_read8(xbuf[cur], wrg * 32 + 16 + lr, kk * 32 + lg * 8);
#pragma unroll
      for (int j = 0; j < 3; ++j) {
        bf16x8 bb = lds_read8(wbuf[cur], TM4[wcg][j] * 16 + lr, kk * 32 + lg * 8);
        acc[0][j] = MFMA(a0, bb, acc[0][j], 0, 0, 0);
        acc[1][j] = MFMA(a1, bb, acc[1][j], 0, 0, 0);
      }
    }
    if (s < 15) {
      writeX(cur ^ 1, (s + 1) % 3);
      writeW(cur ^ 1);
      barrier_lds_only();
    }
  }

  const int ph = (wcg & 1) * 16 + lr;
#pragma unroll
  for (int rg = 0; rg < 2; ++rg) {
    const int rowb = wrg * 32 + rg * 16 + lg * 4;
    const float t_base = (float)(t0 + rowb);
    rope2(acc[rg][0], acc[rg][1], ph, t_base);
    if (wcg < 2) {
#pragma unroll
      for (int r = 0; r < 4; ++r) {
        size_t rowo = (size_t)(r0 + rowb + r) * 64;
        qg[rowo + ph] = f2bf_bits(acc[rg][0][r] * 0.03125f);
        qg[rowo + 32 + ph] = f2bf_bits(acc[rg][1][r] * 0.03125f);
      }
    } else {
#pragma unroll
      for (int r = 0; r < 4; ++r) {
        size_t rowo = (size_t)(r0 + rowb + r) * 64;
        kg[rowo + ph] = f2bf_bits(acc[rg][0][r]);
        kg[rowo + 32 + ph] = f2bf_bits(acc[rg][1][r]);
      }
    }
    {
      const int d = (TM4[wcg][2] - 8) * 16 + lr;
      ushort4 uv;
      uv.x = f2bf_bits(acc[rg][2][0]);
      uv.y = f2bf_bits(acc[rg][2][1]);
      uv.z = f2bf_bits(acc[rg][2][2]);
      uv.w = f2bf_bits(acc[rg][2][3]);
      *(ushort4*)(vtg + (size_t)(b * 64 + d) * 2048 + t0 + rowb) = uv;
    }
  }
}

// ---------------- flash attention split-KV partials (R12 staging + R16 T5
// setprio −2.1us + R17 XCD batch mapping −4.5us: batch b on XCD b, K+Vt 4MB
// working set fits the XCD's 4MB L2).
// Fixed-shift softmax: P = exp(S - 8), cancels exactly in normalization.
// NO cross-block fences (R4: device-scope __threadfence ~400us on gfx950).
__global__ __launch_bounds__(256) void attn_part_kernel(
    const u16* __restrict__ qg, const u16* __restrict__ kg,
    const u16* __restrict__ vtg, u16* __restrict__ opart,
    float* __restrict__ lpart, float* __restrict__ out, int CT, int NCH) {
  const int idx = blockIdx.x;
  const int b = idx & 7;        // XCD-aware: batch = idx mod 8 (grid = 8*256)
  const int rem = idx >> 3;
  const int qt = rem / NCH, ch = rem % NCH;
  const int t0v = ch * CT;
  if (t0v > qt) return;  // uniform early-exit (before any barrier)
  const int t1v = min(qt + 1, t0v + CT);
  const int nv = qt / CT + 1;

  __shared__ __bf16 kbuf[2][64 * 64];
  __shared__ __bf16 vbuf[2][64 * 64];
  __shared__ __bf16 pbuf[4 * 16 * 64];
  const int tid = threadIdx.x;
  const int w = tid >> 6, l = tid & 63;
  const int lr = l & 15, lg = l >> 4;
  const int q0 = qt * 64;
  const float NEG_INF = -__builtin_inff();

  const u16* qrow = qg + (size_t)(b * 2048 + q0 + w * 16 + lr) * 64;
  bf16x8 qf0 = *(const bf16x8*)(qrow + lg * 8);
  bf16x8 qf1 = *(const bf16x8*)(qrow + 32 + lg * 8);

  bf16x8 kr[2], vr[2];
  auto stage_load = [&](int c) {
#pragma unroll
    for (int s = 0; s < 2; ++s) {
      int id = tid + s * 256;
      int row = id >> 3, c8 = id & 7;
      kr[s] = *(const bf16x8*)(kg + (size_t)(b * 2048 + c * 64 + row) * 64 + c8 * 8);
      vr[s] = *(const bf16x8*)(vtg + (size_t)(b * 64 + row) * 2048 + c * 64 + c8 * 8);
    }
  };
  auto stage_write = [&](int bsel) {
#pragma unroll
    for (int s = 0; s < 2; ++s) {
      int id = tid + s * 256;
      int row = id >> 3, c8 = id & 7;
      lds_write8(kbuf[bsel], row, c8 * 8, kr[s]);
      lds_write8(vbuf[bsel], row, c8 * 8, vr[s]);
    }
  };

  f32x4 acc_o[4];
#pragma unroll
  for (int n = 0; n < 4; ++n) acc_o[n] = (f32x4){0.f, 0.f, 0.f, 0.f};
  float l_p[4] = {0.f, 0.f, 0.f, 0.f};  // per-lane partial row sums

  stage_load(t0v);
  stage_write(0);
  __syncthreads();

  for (int c = t0v; c < t1v; ++c) {
    const int cur = (c - t0v) & 1;
    const bool more = (c + 1 < t1v);
    if (more) stage_load(c + 1);  // issue early; hides under QK+exp+PV

    f32x4 s4[4];
    __builtin_amdgcn_s_setprio(1);  // favor this wave while in the MFMA pipe
#pragma unroll
    for (int nt = 0; nt < 4; ++nt) {
      bf16x8 k0 = lds_read8(kbuf[cur], nt * 16 + lr, lg * 8);
      bf16x8 k1 = lds_read8(kbuf[cur], nt * 16 + lr, 32 + lg * 8);
      f32x4 t = (f32x4){0.f, 0.f, 0.f, 0.f};
      t = MFMA(qf0, k0, t, 0, 0, 0);
      t = MFMA(qf1, k1, t, 0, 0, 0);
      s4[nt] = t;
    }
    __builtin_amdgcn_s_setprio(0);
    if (c == qt) {  // causal mask on diagonal tile
#pragma unroll
      for (int nt = 0; nt < 4; ++nt)
#pragma unroll
        for (int r = 0; r < 4; ++r) {
          int kv = nt * 16 + lr, qq = w * 16 + lg * 4 + r;
          if (kv > qq) s4[nt][r] = NEG_INF;
        }
    }
    // P = exp(S - 8); accumulate per-lane row sums (reduced once after loop)
    __bf16* pw = pbuf + w * (16 * 64);
#pragma unroll
    for (int nt = 0; nt < 4; ++nt)
#pragma unroll
      for (int r = 0; r < 4; ++r) {
        float p = __expf(s4[nt][r] - 8.0f);
        l_p[r] += p;
        pw[swz_off(lg * 4 + r, nt * 16 + lr)] = f2bf(p);
      }
    // wave-internal LDS is in-order: no barrier between P write and read
    __builtin_amdgcn_s_setprio(1);
#pragma unroll
    for (int h = 0; h < 2; ++h) {
      bf16x8 pf = lds_read8(pw, lr, h * 32 + lg * 8);
#pragma unroll
      for (int nt = 0; nt < 4; ++nt) {
        bf16x8 vf = lds_read8(vbuf[cur], nt * 16 + lr, h * 32 + lg * 8);
        acc_o[nt] = MFMA(pf, vf, acc_o[nt], 0, 0, 0);
      }
    }
    __builtin_amdgcn_s_setprio(0);
    if (more) {
      stage_write(cur ^ 1);
      __syncthreads();
    }
  }

  // row sums: reduce l_p across the 16 lr lanes (masks 1,2,4,8 stay in group)
  float lsum[4];
#pragma unroll
  for (int r = 0; r < 4; ++r) {
    float s = l_p[r];
    s += __shfl_xor(s, 1);
    s += __shfl_xor(s, 2);
    s += __shfl_xor(s, 4);
    s += __shfl_xor(s, 8);
    lsum[r] = s;
  }

  if (nv == 1) {  // single chunk: normalize and write out directly
#pragma unroll
    for (int r = 0; r < 4; ++r) {
      float inv = 1.0f / lsum[r];
      size_t rowo = (size_t)(b * 2048 + q0 + w * 16 + lg * 4 + r) * 64;
#pragma unroll
      for (int nt = 0; nt < 4; ++nt)
        out[rowo + nt * 16 + lr] = acc_o[nt][r] * inv;
    }
    return;
  }

  // write unnormalized partial (bf16) + row sums (kernel boundary = coherence)
  const size_t slot = (size_t)(b * 32 + qt) * NCH + ch;
  u16* oslot = opart + slot * 4096;
#pragma unroll
  for (int r = 0; r < 4; ++r) {
    int row = w * 16 + lg * 4 + r;
#pragma unroll
    for (int nt = 0; nt < 4; ++nt)
      oslot[row * 64 + nt * 16 + lr] = f2bf_bits(acc_o[nt][r]);
    if (lr == 0) lpart[slot * 64 + row] = lsum[r];
  }
}

// ---------------- combine partials (unweighted ordered sum; same shift in all
// chunks so weights==1): out = sum_c O'_c / sum_c l_c.
// XCD-consistent: b = blockIdx & 7 reads partials from the L2 of the XCD
// where attn_part (same b mapping) wrote them.
__global__ __launch_bounds__(256) void attn_combine_kernel(
    const u16* __restrict__ opart, const float* __restrict__ lpart,
    float* __restrict__ out, int CT, int NCH) {
  const int b = blockIdx.x & 7;
  const int rest = blockIdx.x >> 3;   // 0..127 = qt(32) x quarter(4)
  const int qt = rest >> 2;
  const int quarter = rest & 3;
  const int nv = qt / CT + 1;
  if (nv == 1) return;  // written directly by attn_part
  const int row = quarter * 16 + (threadIdx.x >> 4);
  const int col = (threadIdx.x & 15) * 4;
  const size_t slot0 = (size_t)(b * 32 + qt) * NCH;

  float denom = 0.f;
  float acc[4] = {0.f, 0.f, 0.f, 0.f};
  for (int c = 0; c < nv; ++c) {
    denom += lpart[(slot0 + c) * 64 + row];
    ushort4 pv = *(const ushort4*)(opart + (slot0 + c) * 4096 + row * 64 + col);
    acc[0] += bf2f(pv.x);
    acc[1] += bf2f(pv.y);
    acc[2] += bf2f(pv.z);
    acc[3] += bf2f(pv.w);
  }
  float inv = 1.0f / denom;
  float4 o;
  o.x = acc[0] * inv; o.y = acc[1] * inv; o.z = acc[2] * inv; o.w = acc[3] * inv;
  *(float4*)(out + ((size_t)(b * 2048 + qt * 64 + row)) * 64 + col) = o;
}

extern "C" void kernel_launch(void* const* d_in, const int* in_sizes, int n_in,
                              void* d_out, int out_size, void* d_ws, size_t ws_size,
                              hipStream_t stream) {
  const float* x = (const float*)d_in[0];
  const float* Wq = (const float*)d_in[1];
  const float* Wk = (const float*)d_in[2];
  const float* Wv = (const float*)d_in[3];
  float* out = (float*)d_out;
  char* ws = (char*)d_ws;
  // ws layout: Wt | q | k | vt | Opart | lpart
  u16* wtg = (u16*)ws;                                  // 393216 B
  u16* qg = (u16*)(ws + 393216);                        // 2 MB
  u16* kg = (u16*)(ws + 393216 + 2097152);              // 2 MB
  u16* vtg = (u16*)(ws + 393216 + 2u * 2097152);        // 2 MB
  const size_t base = 393216 + 3u * 2097152;            // 6,684,672 B
  int NCH = 8;  // proven optimum (R11: NCH=16 +5us; R1: no-split +35us)
  // per slot: 8192 B O' + 256 B l
  while (NCH > 1 && base + (size_t)256 * NCH * 8448 > ws_size) NCH >>= 1;
  const int CT = 32 / NCH;
  u16* opart = (u16*)(ws + base);
  float* lpart = (float*)(ws + base + (size_t)256 * NCH * 8192);

  prep_w_kernel<<<dim3(48), dim3(256), 0, stream>>>(Wq, Wk, Wv, wtg);
  qkv_rope_kernel<<<dim3(256), dim3(512), 0, stream>>>(x, wtg, qg, kg, vtg);
  attn_part_kernel<<<dim3(8 * 32 * NCH), dim3(256), 0, stream>>>(
      qg, kg, vtg, opart, lpart, out, CT, NCH);
  attn_combine_kernel<<<dim3(256 * 4), dim3(256), 0, stream>>>(opart, lpart, out, CT, NCH);
}

// Round 19
// 46.102 us; speedup vs baseline: 1.0033x; 1.0033x over previous
//
#include <hip/hip_runtime.h>

typedef __bf16 bf16x8 __attribute__((ext_vector_type(8)));
typedef float f32x4 __attribute__((ext_vector_type(4)));
typedef unsigned short u16;

#define MFMA __builtin_amdgcn_mfma_f32_16x16x32_bf16

__device__ __forceinline__ u16 f2bf_bits(float f) {
  unsigned u = __builtin_bit_cast(unsigned, f);
  u = (u + 0x7fffu + ((u >> 16) & 1u)) >> 16;
  return (u16)u;
}
__device__ __forceinline__ __bf16 f2bf(float f) {
  u16 b = f2bf_bits(f);
  return __builtin_bit_cast(__bf16, b);
}
__device__ __forceinline__ float bf2f(u16 b) {
  return __builtin_bit_cast(float, (unsigned)b << 16);
}

// Barrier that drains ONLY LDS ops (lgkmcnt), leaving global loads (vmcnt) in
// flight across the barrier (T4). Safe when in-flight loads are lane-private.
__device__ __forceinline__ void barrier_lds_only() {
  asm volatile("s_waitcnt lgkmcnt(0)" ::: "memory");
  __builtin_amdgcn_s_barrier();
}

// LDS tiles: logical [R][64] bf16 rows (128 B). XOR-swizzle 16B chunks with row
// to kill the 128B-stride bank conflict on ds_read_b128 (guide G4).
__device__ __forceinline__ int swz_off(int row, int col) {
  return row * 64 + ((((col >> 3) ^ row) & 7) << 3) + (col & 7);
}
__device__ __forceinline__ bf16x8 lds_read8(const __bf16* buf, int row, int col) {
  return *(const bf16x8*)(buf + (row * 64 + ((((col >> 3) ^ row) & 7) << 3)));
}
__device__ __forceinline__ void lds_write8(__bf16* buf, int row, int col, bf16x8 v) {
  *(bf16x8*)(buf + (row * 64 + ((((col >> 3) ^ row) & 7) << 3))) = v;
}

// ---------------- prep: Wt[192][1024] bf16 via coalesced LDS transpose.
__global__ __launch_bounds__(256) void prep_w_kernel(
    const float* __restrict__ Wq, const float* __restrict__ Wk,
    const float* __restrict__ Wv, u16* __restrict__ wtg) {
  __shared__ float tile[64][65];
  const int tid = threadIdx.x;
  const int kt = blockIdx.x & 15;  // 64 k-rows
  const int ct = blockIdx.x >> 4;  // 0=q, 1=k, 2=v
  const float* W = (ct == 0) ? Wq : ((ct == 1) ? Wk : Wv);
  const int k0 = kt * 64;
#pragma unroll
  for (int i = 0; i < 16; ++i) {
    int row = i * 4 + (tid >> 6), col = tid & 63;
    tile[row][col] = W[(size_t)(k0 + row) * 64 + col];
  }
  __syncthreads();
#pragma unroll
  for (int i = 0; i < 16; ++i) {
    int col = i * 4 + (tid >> 6), krow = tid & 63;
    wtg[(size_t)(ct * 64 + col) * 1024 + k0 + krow] = f2bf_bits(tile[krow][col]);
  }
}

// ---------------- fused QKV projection + RoPE (256 blocks x 64 rows).
// R12-proven shape + XCD-consistent batch mapping. DEPTH-3 x prefetch,
// LDS-only barriers, W depth-1. Tile sets keep RoPE pairs (c,c+32)
// lane-local. RoPE trig (index-only) is HOISTED into the prologue so the
// 8 fract+sin+cos chains execute under the x(0)/W(0) load latency instead
// of as a serial epilogue tail after the last barrier.
__global__ __launch_bounds__(512) void qkv_rope_kernel(
    const float* __restrict__ x, const u16* __restrict__ wtg,
    u16* __restrict__ qg, u16* __restrict__ kg, u16* __restrict__ vtg) {
  __shared__ __bf16 xbuf[2][64 * 64];
  __shared__ __bf16 wbuf[2][192 * 64];
  const int tid = threadIdx.x;
  const int w = tid >> 6, l = tid & 63;
  const int wrg = w & 1;
  const int wcg = w >> 1;
  const int lr = l & 15, lg = l >> 4;
  const int b = blockIdx.x & 7;              // XCD-consistent batch mapping
  const int t0 = (blockIdx.x >> 3) * 64;
  const int r0 = b * 2048 + t0;
  constexpr int TM4[4][3] = {{0, 2, 8}, {1, 3, 9}, {4, 6, 10}, {5, 7, 11}};

  f32x4 acc[2][3];
#pragma unroll
  for (int rg = 0; rg < 2; ++rg)
#pragma unroll
    for (int j = 0; j < 3; ++j) acc[rg][j] = (f32x4){0.f, 0.f, 0.f, 0.f};

  const int srow = tid >> 3, sc8 = tid & 7;
  const float* xbase = x + (size_t)(r0 + srow) * 1024 + sc8 * 8;

  float4 xA0, xA1, xB0, xB1, xC0, xC1;
  bf16x8 swr[3];

  auto loadW = [&](int k0) {
#pragma unroll
    for (int s = 0; s < 3; ++s) {
      int id = tid + s * 512;
      swr[s] = *(const bf16x8*)(wtg + (size_t)(id >> 3) * 1024 + k0 + (id & 7) * 8);
    }
  };
  auto writeW = [&](int bsel) {
#pragma unroll
    for (int s = 0; s < 3; ++s) {
      int id = tid + s * 512;
      lds_write8(wbuf[bsel], id >> 3, (id & 7) * 8, swr[s]);
    }
  };
  auto loadX = [&](int step, int sel) {
    const float* p = xbase + (size_t)step * 64;
    if (sel == 0)      { xA0 = *(const float4*)p; xA1 = *(const float4*)(p + 4); }
    else if (sel == 1) { xB0 = *(const float4*)p; xB1 = *(const float4*)(p + 4); }
    else               { xC0 = *(const float4*)p; xC1 = *(const float4*)(p + 4); }
  };
  auto writeX = [&](int bsel, int sel) {
    float4 a0, a1;
    if (sel == 0)      { a0 = xA0; a1 = xA1; }
    else if (sel == 1) { a0 = xB0; a1 = xB1; }
    else               { a0 = xC0; a1 = xC1; }
    bf16x8 v;
    v[0] = f2bf(a0.x); v[1] = f2bf(a0.y); v[2] = f2bf(a0.z); v[3] = f2bf(a0.w);
    v[4] = f2bf(a1.x); v[5] = f2bf(a1.y); v[6] = f2bf(a1.z); v[7] = f2bf(a1.w);
    lds_write8(xbuf[bsel], srow, sc8 * 8, v);
  };

  // prologue: issue x(0)/W(0), then compute RoPE trig UNDER the load latency
  loadX(0, 0);
  loadW(0);

  const int ph = (wcg & 1) * 16 + lr;  // phase index for both q and k tiles
  float cs_[2][4], sn_[2][4];
  {
    const float f = __expf(-(float)ph * 0.28782313662425572f);  // 10000^(-ph/32)
    const float inv2pi = 0.15915494309189535f;
#pragma unroll
    for (int rg = 0; rg < 2; ++rg) {
      const float tb = (float)(t0 + wrg * 32 + rg * 16 + lg * 4);
#pragma unroll
      for (int r = 0; r < 4; ++r) {
        float rev = __builtin_amdgcn_fractf((tb + (float)r) * f * inv2pi);
        sn_[rg][r] = __builtin_amdgcn_sinf(rev);
        cs_[rg][r] = __builtin_amdgcn_cosf(rev);
      }
    }
  }

  writeX(0, 0);
  writeW(0);
  loadX(1, 1);
  loadX(2, 2);
  barrier_lds_only();

#pragma unroll
  for (int s = 0; s < 16; ++s) {
    const int cur = s & 1;
    if (s < 13) loadX(s + 3, s % 3);
    if (s < 15) loadW((s + 1) * 64);
#pragma unroll
    for (int kk = 0; kk < 2; ++kk) {
      bf16x8 a0 = lds_read8(xbuf[cur], wrg * 32 + lr, kk * 32 + lg * 8);
      bf16x8 a1 = lds_read8(xbuf[cur], wrg * 32 + 16 + lr, kk * 32 + lg * 8);
#pragma unroll
      for (int j = 0; j < 3; ++j) {
        bf16x8 bb = lds_read8(wbuf[cur], TM4[wcg][j] * 16 + lr, kk * 32 + lg * 8);
        acc[0][j] = MFMA(a0, bb, acc[0][j], 0, 0, 0);
        acc[1][j] = MFMA(a1, bb, acc[1][j], 0, 0, 0);
      }
    }
    if (s < 15) {
      writeX(cur ^ 1, (s + 1) % 3);
      writeW(cur ^ 1);
      barrier_lds_only();
    }
  }

  // epilogue: apply precomputed RoPE + stores.
#pragma unroll
  for (int rg = 0; rg < 2; ++rg) {
    const int rowb = wrg * 32 + rg * 16 + lg * 4;
#pragma unroll
    for (int r = 0; r < 4; ++r) {  // rotate (lo, hi) with hoisted cs/sn
      float L = acc[rg][0][r], H = acc[rg][1][r];
      acc[rg][0][r] = L * cs_[rg][r] - H * sn_[rg][r];
      acc[rg][1][r] = H * cs_[rg][r] + L * sn_[rg][r];
    }
    if (wcg < 2) {  // q tiles {wcg, wcg+2}; fold scale 2^-5
#pragma unroll
      for (int r = 0; r < 4; ++r) {
        size_t rowo = (size_t)(r0 + rowb + r) * 64;
        qg[rowo + ph] = f2bf_bits(acc[rg][0][r] * 0.03125f);
        qg[rowo + 32 + ph] = f2bf_bits(acc[rg][1][r] * 0.03125f);
      }
    } else {  // k tiles {wcg+2, wcg+4}
#pragma unroll
      for (int r = 0; r < 4; ++r) {
        size_t rowo = (size_t)(r0 + rowb + r) * 64;
        kg[rowo + ph] = f2bf_bits(acc[rg][0][r]);
        kg[rowo + 32 + ph] = f2bf_bits(acc[rg][1][r]);
      }
    }
    {
      const int d = (TM4[wcg][2] - 8) * 16 + lr;
      ushort4 uv;
      uv.x = f2bf_bits(acc[rg][2][0]);
      uv.y = f2bf_bits(acc[rg][2][1]);
      uv.z = f2bf_bits(acc[rg][2][2]);
      uv.w = f2bf_bits(acc[rg][2][3]);
      *(ushort4*)(vtg + (size_t)(b * 64 + d) * 2048 + t0 + rowb) = uv;
    }
  }
}

// ---------------- flash attention split-KV partials (R12 staging + R16 T5
// setprio −2.1us + R17 XCD batch mapping −4.5us: batch b on XCD b, K+Vt 4MB
// working set fits the XCD's 4MB L2).
// Fixed-shift softmax: P = exp(S - 8), cancels exactly in normalization.
// NO cross-block fences (R4: device-scope __threadfence ~400us on gfx950).
__global__ __launch_bounds__(256) void attn_part_kernel(
    const u16* __restrict__ qg, const u16* __restrict__ kg,
    const u16* __restrict__ vtg, u16* __restrict__ opart,
    float* __restrict__ lpart, float* __restrict__ out, int CT, int NCH) {
  const int idx = blockIdx.x;
  const int b = idx & 7;        // XCD-aware: batch = idx mod 8 (grid = 8*256)
  const int rem = idx >> 3;
  const int qt = rem / NCH, ch = rem % NCH;
  const int t0v = ch * CT;
  if (t0v > qt) return;  // uniform early-exit (before any barrier)
  const int t1v = min(qt + 1, t0v + CT);
  const int nv = qt / CT + 1;

  __shared__ __bf16 kbuf[2][64 * 64];
  __shared__ __bf16 vbuf[2][64 * 64];
  __shared__ __bf16 pbuf[4 * 16 * 64];
  const int tid = threadIdx.x;
  const int w = tid >> 6, l = tid & 63;
  const int lr = l & 15, lg = l >> 4;
  const int q0 = qt * 64;
  const float NEG_INF = -__builtin_inff();

  const u16* qrow = qg + (size_t)(b * 2048 + q0 + w * 16 + lr) * 64;
  bf16x8 qf0 = *(const bf16x8*)(qrow + lg * 8);
  bf16x8 qf1 = *(const bf16x8*)(qrow + 32 + lg * 8);

  bf16x8 kr[2], vr[2];
  auto stage_load = [&](int c) {
#pragma unroll
    for (int s = 0; s < 2; ++s) {
      int id = tid + s * 256;
      int row = id >> 3, c8 = id & 7;
      kr[s] = *(const bf16x8*)(kg + (size_t)(b * 2048 + c * 64 + row) * 64 + c8 * 8);
      vr[s] = *(const bf16x8*)(vtg + (size_t)(b * 64 + row) * 2048 + c * 64 + c8 * 8);
    }
  };
  auto stage_write = [&](int bsel) {
#pragma unroll
    for (int s = 0; s < 2; ++s) {
      int id = tid + s * 256;
      int row = id >> 3, c8 = id & 7;
      lds_write8(kbuf[bsel], row, c8 * 8, kr[s]);
      lds_write8(vbuf[bsel], row, c8 * 8, vr[s]);
    }
  };

  f32x4 acc_o[4];
#pragma unroll
  for (int n = 0; n < 4; ++n) acc_o[n] = (f32x4){0.f, 0.f, 0.f, 0.f};
  float l_p[4] = {0.f, 0.f, 0.f, 0.f};  // per-lane partial row sums

  stage_load(t0v);
  stage_write(0);
  __syncthreads();

  for (int c = t0v; c < t1v; ++c) {
    const int cur = (c - t0v) & 1;
    const bool more = (c + 1 < t1v);
    if (more) stage_load(c + 1);  // issue early; hides under QK+exp+PV

    f32x4 s4[4];
    __builtin_amdgcn_s_setprio(1);  // favor this wave while in the MFMA pipe
#pragma unroll
    for (int nt = 0; nt < 4; ++nt) {
      bf16x8 k0 = lds_read8(kbuf[cur], nt * 16 + lr, lg * 8);
      bf16x8 k1 = lds_read8(kbuf[cur], nt * 16 + lr, 32 + lg * 8);
      f32x4 t = (f32x4){0.f, 0.f, 0.f, 0.f};
      t = MFMA(qf0, k0, t, 0, 0, 0);
      t = MFMA(qf1, k1, t, 0, 0, 0);
      s4[nt] = t;
    }
    __builtin_amdgcn_s_setprio(0);
    if (c == qt) {  // causal mask on diagonal tile
#pragma unroll
      for (int nt = 0; nt < 4; ++nt)
#pragma unroll
        for (int r = 0; r < 4; ++r) {
          int kv = nt * 16 + lr, qq = w * 16 + lg * 4 + r;
          if (kv > qq) s4[nt][r] = NEG_INF;
        }
    }
    // P = exp(S - 8); accumulate per-lane row sums (reduced once after loop)
    __bf16* pw = pbuf + w * (16 * 64);
#pragma unroll
    for (int nt = 0; nt < 4; ++nt)
#pragma unroll
      for (int r = 0; r < 4; ++r) {
        float p = __expf(s4[nt][r] - 8.0f);
        l_p[r] += p;
        pw[swz_off(lg * 4 + r, nt * 16 + lr)] = f2bf(p);
      }
    // wave-internal LDS is in-order: no barrier between P write and read
    __builtin_amdgcn_s_setprio(1);
#pragma unroll
    for (int h = 0; h < 2; ++h) {
      bf16x8 pf = lds_read8(pw, lr, h * 32 + lg * 8);
#pragma unroll
      for (int nt = 0; nt < 4; ++nt) {
        bf16x8 vf = lds_read8(vbuf[cur], nt * 16 + lr, h * 32 + lg * 8);
        acc_o[nt] = MFMA(pf, vf, acc_o[nt], 0, 0, 0);
      }
    }
    __builtin_amdgcn_s_setprio(0);
    if (more) {
      stage_write(cur ^ 1);
      __syncthreads();
    }
  }

  // row sums: reduce l_p across the 16 lr lanes (masks 1,2,4,8 stay in group)
  float lsum[4];
#pragma unroll
  for (int r = 0; r < 4; ++r) {
    float s = l_p[r];
    s += __shfl_xor(s, 1);
    s += __shfl_xor(s, 2);
    s += __shfl_xor(s, 4);
    s += __shfl_xor(s, 8);
    lsum[r] = s;
  }

  if (nv == 1) {  // single chunk: normalize and write out directly
#pragma unroll
    for (int r = 0; r < 4; ++r) {
      float inv = 1.0f / lsum[r];
      size_t rowo = (size_t)(b * 2048 + q0 + w * 16 + lg * 4 + r) * 64;
#pragma unroll
      for (int nt = 0; nt < 4; ++nt)
        out[rowo + nt * 16 + lr] = acc_o[nt][r] * inv;
    }
    return;
  }

  // write unnormalized partial (bf16) + row sums (kernel boundary = coherence)
  const size_t slot = (size_t)(b * 32 + qt) * NCH + ch;
  u16* oslot = opart + slot * 4096;
#pragma unroll
  for (int r = 0; r < 4; ++r) {
    int row = w * 16 + lg * 4 + r;
#pragma unroll
    for (int nt = 0; nt < 4; ++nt)
      oslot[row * 64 + nt * 16 + lr] = f2bf_bits(acc_o[nt][r]);
    if (lr == 0) lpart[slot * 64 + row] = lsum[r];
  }
}

// ---------------- combine partials (unweighted ordered sum; same shift in all
// chunks so weights==1): out = sum_c O'_c / sum_c l_c.
// Grid covers ONLY qt >= CT (nv>=2); nv==1 groups were written directly by
// attn_part. XCD-consistent: b = blockIdx & 7 reads partials from the L2 of
// the XCD where attn_part (same b mapping) wrote them.
__global__ __launch_bounds__(256) void attn_combine_kernel(
    const u16* __restrict__ opart, const float* __restrict__ lpart,
    float* __restrict__ out, int CT, int NCH) {
  const int b = blockIdx.x & 7;
  const int rest = blockIdx.x >> 3;   // (qt-CT)(32-CT) x quarter(4)
  const int qt = CT + (rest >> 2);
  const int quarter = rest & 3;
  const int nv = qt / CT + 1;
  const int row = quarter * 16 + (threadIdx.x >> 4);
  const int col = (threadIdx.x & 15) * 4;
  const size_t slot0 = (size_t)(b * 32 + qt) * NCH;

  float denom = 0.f;
  float acc[4] = {0.f, 0.f, 0.f, 0.f};
  for (int c = 0; c < nv; ++c) {
    denom += lpart[(slot0 + c) * 64 + row];
    ushort4 pv = *(const ushort4*)(opart + (slot0 + c) * 4096 + row * 64 + col);
    acc[0] += bf2f(pv.x);
    acc[1] += bf2f(pv.y);
    acc[2] += bf2f(pv.z);
    acc[3] += bf2f(pv.w);
  }
  float inv = 1.0f / denom;
  float4 o;
  o.x = acc[0] * inv; o.y = acc[1] * inv; o.z = acc[2] * inv; o.w = acc[3] * inv;
  *(float4*)(out + ((size_t)(b * 2048 + qt * 64 + row)) * 64 + col) = o;
}

extern "C" void kernel_launch(void* const* d_in, const int* in_sizes, int n_in,
                              void* d_out, int out_size, void* d_ws, size_t ws_size,
                              hipStream_t stream) {
  const float* x = (const float*)d_in[0];
  const float* Wq = (const float*)d_in[1];
  const float* Wk = (const float*)d_in[2];
  const float* Wv = (const float*)d_in[3];
  float* out = (float*)d_out;
  char* ws = (char*)d_ws;
  // ws layout: Wt | q | k | vt | Opart | lpart
  u16* wtg = (u16*)ws;                                  // 393216 B
  u16* qg = (u16*)(ws + 393216);                        // 2 MB
  u16* kg = (u16*)(ws + 393216 + 2097152);              // 2 MB
  u16* vtg = (u16*)(ws + 393216 + 2u * 2097152);        // 2 MB
  const size_t base = 393216 + 3u * 2097152;            // 6,684,672 B
  int NCH = 8;  // proven optimum (R11: NCH=16 +5us; R1: no-split +35us)
  // per slot: 8192 B O' + 256 B l
  while (NCH > 1 && base + (size_t)256 * NCH * 8448 > ws_size) NCH >>= 1;
  const int CT = 32 / NCH;
  u16* opart = (u16*)(ws + base);
  float* lpart = (float*)(ws + base + (size_t)256 * NCH * 8192);

  prep_w_kernel<<<dim3(48), dim3(256), 0, stream>>>(Wq, Wk, Wv, wtg);
  qkv_rope_kernel<<<dim3(256), dim3(512), 0, stream>>>(x, wtg, qg, kg, vtg);
  attn_part_kernel<<<dim3(8 * 32 * NCH), dim3(256), 0, stream>>>(
      qg, kg, vtg, opart, lpart, out, CT, NCH);
  if (NCH > 1) {
    const int nqt = 32 - CT;  // q-tiles needing a combine (nv >= 2)
    attn_combine_kernel<<<dim3(8 * nqt * 4), dim3(256), 0, stream>>>(
        opart, lpart, out, CT, NCH);
  }
}